// Round 5
// baseline (43.604 us; speedup 1.0000x reference)
//
#include <hip/hip_runtime.h>
#include <math.h>

#define N_KEYS 8192
#define DIM    1024
#define BQ     64
#define TOPK   4
#define HD     512
#define KSPLIT 8
#define KSLICE (DIM / KSPLIT)   // 128 dims per block
#define NBLK   64               // keys per block (16 per wave)

typedef _Float16 half8 __attribute__((ext_vector_type(8)));
typedef _Float16 half4 __attribute__((ext_vector_type(4)));
typedef float    f32x4 __attribute__((ext_vector_type(4)));

#if defined(__has_builtin)
#if __has_builtin(__builtin_amdgcn_global_load_lds)
#define HAS_GLLDS 1
#endif
#endif

__device__ __forceinline__ bool better(float av, int ai, float bv, int bi) {
    return (av > bv) || (av == bv && ai < bi);
}

__device__ __forceinline__ void ce(float& av, int& ai, float& bv, int& bi) {
    if (!better(av, ai, bv, bi)) {
        float tv = av; av = bv; bv = tv;
        int   ti = ai; ai = bi; bi = ti;
    }
}

__device__ __forceinline__ void merge_shfl(float v[4], int ix[4], int off) {
    float pv[4]; int pi[4];
    #pragma unroll
    for (int r = 0; r < 4; ++r) {
        pv[r] = __shfl_xor(v[r], off);
        pi[r] = __shfl_xor(ix[r], off);
    }
    float nv[4]; int ni[4];
    #pragma unroll
    for (int r = 0; r < 4; ++r) {
        bool ta = better(v[r], ix[r], pv[3 - r], pi[3 - r]);
        nv[r] = ta ? v[r]  : pv[3 - r];
        ni[r] = ta ? ix[r] : pi[3 - r];
    }
    ce(nv[0], ni[0], nv[2], ni[2]);
    ce(nv[1], ni[1], nv[3], ni[3]);
    ce(nv[0], ni[0], nv[1], ni[1]);
    ce(nv[2], ni[2], nv[3], ni[3]);
    #pragma unroll
    for (int r = 0; r < 4; ++r) { v[r] = nv[r]; ix[r] = ni[r]; }
}

// ---------------- prep: eq = exp(q) split into hi/lo f16 ----------------
__global__ __launch_bounds__(256) void prep_q(const float4* __restrict__ q4,
                                              _Float16* __restrict__ eqh,
                                              _Float16* __restrict__ eql) {
    int i = blockIdx.x * 256 + threadIdx.x;    // 64 blocks -> 16384 float4
    float4 v = q4[i];
    float e0 = expf(v.x), e1 = expf(v.y), e2 = expf(v.z), e3 = expf(v.w);
    half4 h, l;
    h[0] = (_Float16)e0; h[1] = (_Float16)e1; h[2] = (_Float16)e2; h[3] = (_Float16)e3;
    l[0] = (_Float16)(e0 - (float)h[0]); l[1] = (_Float16)(e1 - (float)h[1]);
    l[2] = (_Float16)(e2 - (float)h[2]); l[3] = (_Float16)(e3 - (float)h[3]);
    *(half4*)&eqh[i * 4] = h;
    *(half4*)&eql[i * 4] = l;
}

// ---------------- scores: barrier-free, wave-independent split-f16 MFMA ----------
// part[slice][b][key] = sum_{d in slice} exp(q[b,d]) * exp(k[key,d])
// Per-wave LDS layout: 16 rows x 32 f32-groups; group g of row r stored at
// physical p = (g&24) | ((g+r)&7)  (rotation keeps async-write linear AND
// fragment reads bank-uniform).
__global__ __launch_bounds__(256, 4) void scores_mfma(
        const _Float16* __restrict__ eqh, const _Float16* __restrict__ eql,
        const float* __restrict__ keys, float* __restrict__ part) {
    __shared__ float Braw[4 * 16 * 32 * 4];   // 4 waves x 8 KB = 32 KB

    const int t    = threadIdx.x;
    const int lane = t & 63, w = t >> 6;
    const int l15  = lane & 15, l4 = lane >> 4, r7 = lane & 7;
    const int i0    = blockIdx.x * NBLK;
    const int dbase = blockIdx.y * KSLICE;

    float* wbase = &Braw[w * 2048];

    // ---- stage this wave's 16 keys x 128 dims (raw f32, rotated layout) ----
    #pragma unroll
    for (int j = 0; j < 8; ++j) {
        int s   = j * 64 + lane;        // 0..511 slots (16B each)
        int row = s >> 5;               // 0..15
        int p   = s & 31;
        int g   = (p & 24) | ((p - row) & 7);
        const float* src = keys + (size_t)(i0 + 16 * w + row) * DIM + dbase + g * 4;
#ifdef HAS_GLLDS
        __builtin_amdgcn_global_load_lds(
            (const __attribute__((address_space(1))) void*)src,
            (__attribute__((address_space(3))) void*)(wbase + j * 256), 16, 0, 0);
#else
        *(float4*)(wbase + s * 4) = *(const float4*)src;
#endif
    }
#ifdef HAS_GLLDS
    asm volatile("s_waitcnt vmcnt(0)" ::: "memory");
    __builtin_amdgcn_sched_barrier(0);
#endif

    f32x4 acc[4] = {};

    #pragma unroll
    for (int ks = 0; ks < 4; ++ks) {
        // B fragment: key = l15, dims ks*32 + l4*8 .. +8  (two rotated b128 reads)
        int p0 = ks * 8 + ((2 * l4 + 0 + r7) & 7);
        int p1 = ks * 8 + ((2 * l4 + 1 + r7) & 7);
        float4 b0 = *(const float4*)&wbase[l15 * 128 + p0 * 4];
        float4 b1 = *(const float4*)&wbase[l15 * 128 + p1 * 4];
        float e[8] = {__expf(b0.x), __expf(b0.y), __expf(b0.z), __expf(b0.w),
                      __expf(b1.x), __expf(b1.y), __expf(b1.z), __expf(b1.w)};
        half8 Bh, Bl;
        #pragma unroll
        for (int j = 0; j < 8; ++j) {
            _Float16 h = (_Float16)e[j];
            Bh[j] = h;
            Bl[j] = (_Float16)(e[j] - (float)h);
        }
        #pragma unroll
        for (int mt = 0; mt < 4; ++mt) {
            const size_t aoff = (size_t)(16 * mt + l15) * DIM + dbase + ks * 32 + l4 * 8;
            half8 Ah = *(const half8*)&eqh[aoff];
            half8 Al = *(const half8*)&eql[aoff];
            acc[mt] = __builtin_amdgcn_mfma_f32_16x16x32_f16(Ah, Bh, acc[mt], 0, 0, 0);
            acc[mt] = __builtin_amdgcn_mfma_f32_16x16x32_f16(Ah, Bl, acc[mt], 0, 0, 0);
            acc[mt] = __builtin_amdgcn_mfma_f32_16x16x32_f16(Al, Bh, acc[mt], 0, 0, 0);
        }
    }

    // ---- epilogue: C layout col=lane&15, row=(lane>>4)*4+reg ----
    float* pb = part + (size_t)blockIdx.y * (BQ * N_KEYS) + i0 + 16 * w + l15;
    #pragma unroll
    for (int mt = 0; mt < 4; ++mt)
        #pragma unroll
        for (int r = 0; r < 4; ++r)
            pb[(size_t)(16 * mt + l4 * 4 + r) * N_KEYS] = acc[mt][r];
}

// ---------------- topk partial: per (b, quarter-of-keys) sorted top-4 ----------------
template<int KS>
__global__ __launch_bounds__(1024) void topk_partial(const float* __restrict__ part,
                                                     float* __restrict__ cv,
                                                     int* __restrict__ ci) {
    const int b     = blockIdx.x >> 2;
    const int chunk = blockIdx.x & 3;
    const int t     = threadIdx.x;
    const int lane  = t & 63, wid = t >> 6;

    __shared__ float sv[16][4];
    __shared__ int   si[16][4];

    float v[4]  = {-INFINITY, -INFINITY, -INFINITY, -INFINITY};
    int   ix[4] = {0x7fffffff, 0x7fffffff, 0x7fffffff, 0x7fffffff};

    const float* pb = part + (size_t)b * N_KEYS;
    #pragma unroll
    for (int r = 0; r < 2; ++r) {
        int i = chunk * 2048 + t + r * 1024;
        float s = 0.f;
        #pragma unroll
        for (int sl = 0; sl < KS; ++sl)
            s += pb[(size_t)sl * (BQ * N_KEYS) + i];
        if (better(s, i, v[3], ix[3])) {
            v[3] = s; ix[3] = i;
            #pragma unroll
            for (int p = 3; p > 0; --p) {
                if (better(v[p], ix[p], v[p - 1], ix[p - 1])) {
                    float tv = v[p]; v[p] = v[p-1]; v[p-1] = tv;
                    int   ti = ix[p]; ix[p] = ix[p-1]; ix[p-1] = ti;
                }
            }
        }
    }
    merge_shfl(v, ix, 1);  merge_shfl(v, ix, 2);  merge_shfl(v, ix, 4);
    merge_shfl(v, ix, 8);  merge_shfl(v, ix, 16); merge_shfl(v, ix, 32);

    if (lane == 0) {
        #pragma unroll
        for (int r = 0; r < 4; ++r) { sv[wid][r] = v[r]; si[wid][r] = ix[r]; }
    }
    __syncthreads();

    if (wid == 0) {
        float mv[4]; int mi[4];
        if (lane < 16) {
            #pragma unroll
            for (int r = 0; r < 4; ++r) { mv[r] = sv[lane][r]; mi[r] = si[lane][r]; }
        } else {
            #pragma unroll
            for (int r = 0; r < 4; ++r) { mv[r] = -INFINITY; mi[r] = 0x7fffffff; }
        }
        merge_shfl(mv, mi, 1); merge_shfl(mv, mi, 2);
        merge_shfl(mv, mi, 4); merge_shfl(mv, mi, 8);
        if (lane == 0) {
            #pragma unroll
            for (int r = 0; r < 4; ++r) {
                cv[blockIdx.x * 4 + r] = mv[r];
                ci[blockIdx.x * 4 + r] = mi[r];
            }
        }
    }
}

// ---------------- finalize: merge 4 chunk-lists, softmax, gather ----------------
__global__ __launch_bounds__(64) void finalize_kernel(const float* __restrict__ cv,
                                                      const int* __restrict__ ci,
                                                      const float* __restrict__ theta,
                                                      const float* __restrict__ mag,
                                                      float* __restrict__ out) {
    const int b    = blockIdx.x;
    const int lane = threadIdx.x;

    __shared__ float fw[4];
    __shared__ int   fi[4];

    float v[4]  = {-INFINITY, -INFINITY, -INFINITY, -INFINITY};
    int   ix[4] = {0x7fffffff, 0x7fffffff, 0x7fffffff, 0x7fffffff};
    if (lane < 4) {
        #pragma unroll
        for (int r = 0; r < 4; ++r) {
            v[r]  = cv[(b * 4 + lane) * 4 + r];
            ix[r] = ci[(b * 4 + lane) * 4 + r];
        }
    }
    merge_shfl(v, ix, 1); merge_shfl(v, ix, 2);

    if (lane == 0) {
        float ssum = v[0] + v[1] + v[2] + v[3];   // positive exp-sums
        #pragma unroll
        for (int r = 0; r < 4; ++r) { fw[r] = v[r] / ssum; fi[r] = ix[r]; }
    }
    __syncthreads();

    const float4* th4 = (const float4*)theta;
    float4* out4 = (float4*)out;
    #pragma unroll
    for (int r = 0; r < 8; ++r) {
        int l = lane + r * 64;
        int j = l >> 7, c4 = l & 127;
        out4[((size_t)b * TOPK + j) * (HD / 4) + c4] = th4[(size_t)fi[j] * (HD / 4) + c4];
    }
    if (lane < TOPK) {
        out[(size_t)BQ * TOPK * HD + b * TOPK + lane]             = mag[fi[lane]];
        out[(size_t)BQ * TOPK * HD + BQ * TOPK + b * TOPK + lane] = fw[lane];
    }
}

extern "C" void kernel_launch(void* const* d_in, const int* in_sizes, int n_in,
                              void* d_out, int out_size, void* d_ws, size_t ws_size,
                              hipStream_t stream) {
    const float* q     = (const float*)d_in[0];
    const float* keys  = (const float*)d_in[1];
    const float* theta = (const float*)d_in[2];
    const float* mag   = (const float*)d_in[3];
    float* out = (float*)d_out;

    float*    part = (float*)d_ws;                              // 8 * 2MB = 16MB
    _Float16* eqh  = (_Float16*)(part + (size_t)KSPLIT * BQ * N_KEYS);
    _Float16* eql  = eqh + (size_t)BQ * DIM;
    float*    cv   = (float*)(eql + (size_t)BQ * DIM);
    int*      ci   = (int*)(cv + BQ * 4 * TOPK);

    prep_q<<<BQ * DIM / 4 / 256, 256, 0, stream>>>((const float4*)q, eqh, eql);
    scores_mfma<<<dim3(N_KEYS / NBLK, KSPLIT), 256, 0, stream>>>(eqh, eql, keys, part);
    topk_partial<KSPLIT><<<BQ * 4, 1024, 0, stream>>>(part, cv, ci);
    finalize_kernel<<<BQ, 64, 0, stream>>>(cv, ci, theta, mag, out);
}

// Round 6
// 36.092 us; speedup vs baseline: 1.2081x; 1.2081x over previous
//
#include <hip/hip_runtime.h>
#include <math.h>

#define N_KEYS  8192
#define DIM     1024
#define BQ      64
#define TOPK    4
#define HD      512
#define NBLK    16
#define NBLOCKS (N_KEYS / NBLK)     // 512
#define CD      128                 // dims per chunk
#define NCHUNK  (DIM / CD)          // 8
#define SCP     (NBLK + 1)          // padded score stride

typedef _Float16 half8 __attribute__((ext_vector_type(8)));
typedef _Float16 half4 __attribute__((ext_vector_type(4)));
typedef float    f32x4 __attribute__((ext_vector_type(4)));

__device__ __forceinline__ bool better(float av, int ai, float bv, int bi) {
    return (av > bv) || (av == bv && ai < bi);
}

__device__ __forceinline__ void ce(float& av, int& ai, float& bv, int& bi) {
    if (!better(av, ai, bv, bi)) {
        float tv = av; av = bv; bv = tv;
        int   ti = ai; ai = bi; bi = ti;
    }
}

__device__ __forceinline__ void ins4(float v[4], int ix[4], float s, int gi) {
    if (better(s, gi, v[3], ix[3])) {
        v[3] = s; ix[3] = gi;
        #pragma unroll
        for (int p = 3; p > 0; --p) {
            if (better(v[p], ix[p], v[p - 1], ix[p - 1])) {
                float tv = v[p]; v[p] = v[p-1]; v[p-1] = tv;
                int   ti = ix[p]; ix[p] = ix[p-1]; ix[p-1] = ti;
            }
        }
    }
}

__device__ __forceinline__ void merge_shfl(float v[4], int ix[4], int off) {
    float pv[4]; int pi[4];
    #pragma unroll
    for (int r = 0; r < 4; ++r) {
        pv[r] = __shfl_xor(v[r], off);
        pi[r] = __shfl_xor(ix[r], off);
    }
    float nv[4]; int ni[4];
    #pragma unroll
    for (int r = 0; r < 4; ++r) {
        bool ta = better(v[r], ix[r], pv[3 - r], pi[3 - r]);
        nv[r] = ta ? v[r]  : pv[3 - r];
        ni[r] = ta ? ix[r] : pi[3 - r];
    }
    ce(nv[0], ni[0], nv[2], ni[2]);
    ce(nv[1], ni[1], nv[3], ni[3]);
    ce(nv[0], ni[0], nv[1], ni[1]);
    ce(nv[2], ni[2], nv[3], ni[3]);
    #pragma unroll
    for (int r = 0; r < 4; ++r) { v[r] = nv[r]; ix[r] = ni[r]; }
}

// ---------------- prep: eq = exp(q) split into hi/lo f16 ----------------
__global__ __launch_bounds__(256) void prep_q(const float4* __restrict__ q4,
                                              _Float16* __restrict__ eqh,
                                              _Float16* __restrict__ eql) {
    int i = blockIdx.x * 256 + threadIdx.x;    // 64 blocks -> 16384 float4
    float4 v = q4[i];
    float e0 = __expf(v.x), e1 = __expf(v.y), e2 = __expf(v.z), e3 = __expf(v.w);
    half4 h, l;
    h[0] = (_Float16)e0; h[1] = (_Float16)e1; h[2] = (_Float16)e2; h[3] = (_Float16)e3;
    l[0] = (_Float16)(e0 - (float)h[0]); l[1] = (_Float16)(e1 - (float)h[1]);
    l[2] = (_Float16)(e2 - (float)h[2]); l[3] = (_Float16)(e3 - (float)h[3]);
    *(half4*)&eqh[i * 4] = h;
    *(half4*)&eql[i * 4] = l;
}

// -------- fused: scores (split-f16 3-MFMA) + per-block top-4 per query --------
// Block = 16 keys x 64 queries x 1024 dims. Writes 4 candidates per (q, block).
__global__ __launch_bounds__(256, 2) void fused_scores_topk(
        const _Float16* __restrict__ eqh, const _Float16* __restrict__ eql,
        const float* __restrict__ keys,
        float* __restrict__ cv, int* __restrict__ ci) {
    __shared__ _Float16 Bh[2][NBLK * CD];   // 4 KB per buffer
    __shared__ _Float16 Bl[2][NBLK * CD];
    __shared__ float sc[BQ * SCP];          // 64 x 17 f32

    const int t    = threadIdx.x;
    const int lane = t & 63, w = t >> 6;    // 4 waves, wave w owns q rows 16w..16w+15
    const int l15  = lane & 15, l4 = lane >> 4;
    const int i0   = blockIdx.x * NBLK;

    // staging map: thread t handles key row t>>4, dim-group t&15 (8 dims, 32B)
    const int srow = t >> 4, sg = t & 15;
    const int sgp  = (sg & 8) | ((sg ^ srow) & 7);   // XOR swizzle on 16B groups
    const float* ksrc = keys + (size_t)(i0 + srow) * DIM + sg * 8;

    const int arow = 16 * w + l15;
    const _Float16* aph = eqh + (size_t)arow * DIM + l4 * 8;
    const _Float16* apl = eql + (size_t)arow * DIM + l4 * 8;

    float4 r0, r1;
    half8 ah[2][4], al[2][4];

#define LOADK(c) do { \
        const float* s_ = ksrc + (c) * CD; \
        r0 = *(const float4*)s_; r1 = *(const float4*)(s_ + 4); \
    } while (0)

#define LOADA(c, pb) do { \
        _Pragma("unroll") \
        for (int ks_ = 0; ks_ < 4; ++ks_) { \
            ah[pb][ks_] = *(const half8*)(aph + (c) * CD + ks_ * 32); \
            al[pb][ks_] = *(const half8*)(apl + (c) * CD + ks_ * 32); \
        } \
    } while (0)

#define WRITEK(buf) do { \
        float e_[8] = {__expf(r0.x), __expf(r0.y), __expf(r0.z), __expf(r0.w), \
                       __expf(r1.x), __expf(r1.y), __expf(r1.z), __expf(r1.w)}; \
        half8 h_, l_; \
        _Pragma("unroll") \
        for (int j_ = 0; j_ < 8; ++j_) { \
            _Float16 hh_ = (_Float16)e_[j_]; \
            h_[j_] = hh_; \
            l_[j_] = (_Float16)(e_[j_] - (float)hh_); \
        } \
        *(half8*)&Bh[buf][srow * CD + sgp * 8] = h_; \
        *(half8*)&Bl[buf][srow * CD + sgp * 8] = l_; \
    } while (0)

    // prologue: chunk 0
    LOADK(0);
    LOADA(0, 0);
    WRITEK(0);
    __syncthreads();

    f32x4 acc0 = {0.f, 0.f, 0.f, 0.f};
    f32x4 acc1 = {0.f, 0.f, 0.f, 0.f};
    f32x4 acc2 = {0.f, 0.f, 0.f, 0.f};

    const int rmask = l15 & 7;   // B-row (key) swizzle component

    #pragma unroll
    for (int c = 0; c < NCHUNK; ++c) {
        const int buf = c & 1;
        if (c + 1 < NCHUNK) {
            LOADK(c + 1);            // keys for chunk c+1 (HBM, in flight over MFMAs)
            LOADA(c + 1, buf ^ 1);   // A fragments for chunk c+1 (L2)
        }
        #pragma unroll
        for (int ks = 0; ks < 4; ++ks) {
            int g  = ks * 4 + l4;
            int gp = (g & 8) | ((g ^ rmask) & 7);
            half8 bh = *(const half8*)&Bh[buf][l15 * CD + gp * 8];
            half8 bl = *(const half8*)&Bl[buf][l15 * CD + gp * 8];
            acc0 = __builtin_amdgcn_mfma_f32_16x16x32_f16(ah[buf][ks], bh, acc0, 0, 0, 0);
            acc1 = __builtin_amdgcn_mfma_f32_16x16x32_f16(ah[buf][ks], bl, acc1, 0, 0, 0);
            acc2 = __builtin_amdgcn_mfma_f32_16x16x32_f16(al[buf][ks], bh, acc2, 0, 0, 0);
        }
        if (c + 1 < NCHUNK) WRITEK(buf ^ 1);
        __syncthreads();
    }

    // scores to LDS: C layout col(key)=l15, row(q)=l4*4+r within wave's 16 rows
    #pragma unroll
    for (int r = 0; r < 4; ++r)
        sc[(16 * w + l4 * 4 + r) * SCP + l15] = acc0[r] + acc1[r] + acc2[r];
    __syncthreads();

    // per-q top-4 over this block's 16 keys: 4 threads per q, 4 keys each
    {
        const int q = t >> 2, sub = t & 3;
        float v[4]  = {-INFINITY, -INFINITY, -INFINITY, -INFINITY};
        int   ix[4] = {0x7fffffff, 0x7fffffff, 0x7fffffff, 0x7fffffff};
        #pragma unroll
        for (int j = 0; j < 4; ++j) {
            int kl = sub * 4 + j;
            ins4(v, ix, sc[q * SCP + kl], i0 + kl);
        }
        merge_shfl(v, ix, 1);
        merge_shfl(v, ix, 2);
        if (sub == 0) {
            float4 vv = make_float4(v[0], v[1], v[2], v[3]);
            int4   ii = make_int4(ix[0], ix[1], ix[2], ix[3]);
            ((float4*)cv)[q * NBLOCKS + blockIdx.x] = vv;
            ((int4*)ci)[q * NBLOCKS + blockIdx.x]   = ii;
        }
    }
#undef LOADK
#undef LOADA
#undef WRITEK
}

// ---------------- finalize: merge 512 sorted-4 lists per b, softmax, gather ----
__global__ __launch_bounds__(256) void finalize_kernel(
        const float* __restrict__ cv, const int* __restrict__ ci,
        const float* __restrict__ theta, const float* __restrict__ mag,
        float* __restrict__ out) {
    const int b = blockIdx.x;
    const int t = threadIdx.x;
    const int lane = t & 63, wid = t >> 6;

    __shared__ float sv[4][4];
    __shared__ int   si[4][4];
    __shared__ float fw[4];
    __shared__ int   fi[4];

    // each thread merges 2 of the 512 sorted lists
    float4 va = ((const float4*)cv)[b * NBLOCKS + t];
    int4   ia = ((const int4*)ci)[b * NBLOCKS + t];
    float4 vb = ((const float4*)cv)[b * NBLOCKS + 256 + t];
    int4   ib = ((const int4*)ci)[b * NBLOCKS + 256 + t];

    float v[4]  = {va.x, va.y, va.z, va.w};
    int   ix[4] = {ia.x, ia.y, ia.z, ia.w};
    ins4(v, ix, vb.x, ib.x);
    ins4(v, ix, vb.y, ib.y);
    ins4(v, ix, vb.z, ib.z);
    ins4(v, ix, vb.w, ib.w);

    merge_shfl(v, ix, 1);  merge_shfl(v, ix, 2);  merge_shfl(v, ix, 4);
    merge_shfl(v, ix, 8);  merge_shfl(v, ix, 16); merge_shfl(v, ix, 32);

    if (lane == 0) {
        #pragma unroll
        for (int r = 0; r < 4; ++r) { sv[wid][r] = v[r]; si[wid][r] = ix[r]; }
    }
    __syncthreads();

    if (wid == 0) {
        float mv[4]; int mi[4];
        if (lane < 4) {
            #pragma unroll
            for (int r = 0; r < 4; ++r) { mv[r] = sv[lane][r]; mi[r] = si[lane][r]; }
        } else {
            #pragma unroll
            for (int r = 0; r < 4; ++r) { mv[r] = -INFINITY; mi[r] = 0x7fffffff; }
        }
        merge_shfl(mv, mi, 1); merge_shfl(mv, mi, 2);
        if (lane == 0) {
            float ssum = mv[0] + mv[1] + mv[2] + mv[3];   // positive exp-sums
            #pragma unroll
            for (int r = 0; r < 4; ++r) { fw[r] = mv[r] / ssum; fi[r] = mi[r]; }
        }
    }
    __syncthreads();

    const float4* th4 = (const float4*)theta;
    float4* out4 = (float4*)out;
    #pragma unroll
    for (int r = 0; r < 2; ++r) {
        int l = t + r * 256;          // 0..511
        int j = l >> 7, c4 = l & 127;
        out4[((size_t)b * TOPK + j) * (HD / 4) + c4] = th4[(size_t)fi[j] * (HD / 4) + c4];
    }
    if (t < TOPK) {
        out[(size_t)BQ * TOPK * HD + b * TOPK + t]             = mag[fi[t]];
        out[(size_t)BQ * TOPK * HD + BQ * TOPK + b * TOPK + t] = fw[t];
    }
}

extern "C" void kernel_launch(void* const* d_in, const int* in_sizes, int n_in,
                              void* d_out, int out_size, void* d_ws, size_t ws_size,
                              hipStream_t stream) {
    const float* q     = (const float*)d_in[0];
    const float* keys  = (const float*)d_in[1];
    const float* theta = (const float*)d_in[2];
    const float* mag   = (const float*)d_in[3];
    float* out = (float*)d_out;

    _Float16* eqh = (_Float16*)d_ws;                         // 128 KB
    _Float16* eql = eqh + (size_t)BQ * DIM;                  // 128 KB
    float*    cv  = (float*)(eql + (size_t)BQ * DIM);        // 64*512*4 f32 = 512 KB
    int*      ci  = (int*)(cv + (size_t)BQ * NBLOCKS * 4);   // 512 KB

    prep_q<<<BQ * DIM / 4 / 256, 256, 0, stream>>>((const float4*)q, eqh, eql);
    fused_scores_topk<<<NBLOCKS, 256, 0, stream>>>(eqh, eql, keys, cv, ci);
    finalize_kernel<<<BQ, 256, 0, stream>>>(cv, ci, theta, mag, out);
}